// Round 1
// baseline (516.879 us; speedup 1.0000x reference)
//
#include <hip/hip_runtime.h>
#include <hip/hip_bf16.h>
#include <stdint.h>

typedef __attribute__((ext_vector_type(8))) short short8;
typedef __attribute__((ext_vector_type(4))) float f32x4;
typedef __attribute__((ext_vector_type(4))) unsigned short ushort4v;

#define N_NODES 16384
#define D_IN    512
#define D_HID   256
#define D_OUT   64
#define S_SAMP  4096

__device__ __forceinline__ unsigned short f2bf(float f) {
  union { float f; uint32_t u; } v; v.f = f;
  uint32_t u = v.u;
  u += 0x7FFFu + ((u >> 16) & 1u);   // round-to-nearest-even
  return (unsigned short)(u >> 16);
}

// C += scale * (A_f32[arow? gathered rows] converted to bf16) @ B_bf16[K x N]
// Grid = (M/BM) * kChunks. Output via f32 atomics (C must be pre-zeroed).
template<int BM, int BN, int BK>
__global__ __launch_bounds__(256)
void gemm_bf16_atomic(const float* __restrict__ A, int lda,
                      const int* __restrict__ arow,
                      const unsigned short* __restrict__ B, int ldb,
                      float* __restrict__ C, int ldc,
                      int M, int K, int kChunks, float scale)
{
  static_assert(BM == 64 && BK == 64 && (BN == 64 || BN == 256), "tile");
  const int mt  = blockIdx.x / kChunks;
  const int kc  = blockIdx.x % kChunks;
  const int kLen = K / kChunks;
  const int k0b  = kc * kLen;
  const int tid  = threadIdx.x;
  const int lane = tid & 63;
  const int wid  = tid >> 6;
  const int l16  = lane & 15;
  const int lg   = lane >> 4;

  __shared__ unsigned short As[BM * BK];   // swizzled: 16B chunk g stored at g^(row&7)
  __shared__ unsigned short Bs[BN * BK];   // transposed [n][k], same swizzle

  constexpr int WN  = (BN == 256) ? 4 : 2;
  constexpr int WM  = 4 / WN;
  constexpr int WTM = BM / WM;
  constexpr int WTN = BN / WN;
  constexpr int MF  = WTM / 16;
  constexpr int NF  = WTN / 16;
  const int wrow = wid / WN;
  const int wcol = wid % WN;

  f32x4 acc[MF][NF] = {};

  // A staging mapping: 256 threads x 16 f32 = 64x64 tile
  const int am   = tid >> 2;
  const int aseg = tid & 3;
  const int arowIdx = mt * BM + am;
  const size_t rowg = arow ? (size_t)arow[arowIdx] : (size_t)arowIdx;
  const float* aBase = A + rowg * (size_t)lda + k0b + aseg * 16;

  // B staging mapping
  constexpr int NSEG   = BN / 8;
  constexpr int KROWS  = 256 / NSEG;
  constexpr int PASSES = BK / KROWS;
  const int nseg = tid % NSEG;
  const int krow = tid / NSEG;

  for (int ks = 0; ks < kLen; ks += BK) {
    __syncthreads();
    { // ---- stage A: f32 -> bf16, swizzled 16B chunks ----
      const float* ap = aBase + ks;
      f32x4 v0 = *(const f32x4*)(ap + 0);
      f32x4 v1 = *(const f32x4*)(ap + 4);
      f32x4 v2 = *(const f32x4*)(ap + 8);
      f32x4 v3 = *(const f32x4*)(ap + 12);
      short8 s0, s1;
      s0[0]=f2bf(v0[0]); s0[1]=f2bf(v0[1]); s0[2]=f2bf(v0[2]); s0[3]=f2bf(v0[3]);
      s0[4]=f2bf(v1[0]); s0[5]=f2bf(v1[1]); s0[6]=f2bf(v1[2]); s0[7]=f2bf(v1[3]);
      s1[0]=f2bf(v2[0]); s1[1]=f2bf(v2[1]); s1[2]=f2bf(v2[2]); s1[3]=f2bf(v2[3]);
      s1[4]=f2bf(v3[0]); s1[5]=f2bf(v3[1]); s1[6]=f2bf(v3[2]); s1[7]=f2bf(v3[3]);
      const int g0 = (aseg * 2)     ^ (am & 7);
      const int g1 = (aseg * 2 + 1) ^ (am & 7);
      *(short8*)&As[am * BK + g0 * 8] = s0;
      *(short8*)&As[am * BK + g1 * 8] = s1;
    }
    { // ---- stage B: bf16 [BK x BN] -> transposed swizzled Bs[n][k] ----
      #pragma unroll
      for (int p = 0; p < PASSES; ++p) {
        const int k = krow + p * KROWS;
        const unsigned short* bp = B + (size_t)(k0b + ks + k) * ldb + nseg * 8;
        short8 v = *(const short8*)bp;
        const int kcnk = k >> 3, ke = k & 7;
        #pragma unroll
        for (int i = 0; i < 8; ++i) {
          const int j = (i + nseg) & 7;   // rotate to spread LDS banks
          const int n = nseg * 8 + j;
          Bs[n * BK + ((kcnk ^ (n & 7)) * 8 + ke)] = (unsigned short)v[j];
        }
      }
    }
    __syncthreads();
    // ---- compute ----
    #pragma unroll
    for (int kk = 0; kk < BK / 32; ++kk) {
      const int gk = kk * 4 + lg;
      short8 af[MF], bfr[NF];
      #pragma unroll
      for (int fm = 0; fm < MF; ++fm) {
        const int m = wrow * WTM + fm * 16 + l16;
        af[fm] = *(const short8*)&As[m * BK + ((gk ^ (m & 7)) * 8)];
      }
      #pragma unroll
      for (int fn = 0; fn < NF; ++fn) {
        const int n = wcol * WTN + fn * 16 + l16;
        bfr[fn] = *(const short8*)&Bs[n * BK + ((gk ^ (n & 7)) * 8)];
      }
      #pragma unroll
      for (int fm = 0; fm < MF; ++fm)
        #pragma unroll
        for (int fn = 0; fn < NF; ++fn)
          acc[fm][fn] = __builtin_amdgcn_mfma_f32_16x16x32_bf16(
              af[fm], bfr[fn], acc[fm][fn], 0, 0, 0);
    }
  }
  // ---- epilogue: scaled f32 atomic add ----
  #pragma unroll
  for (int fm = 0; fm < MF; ++fm)
    #pragma unroll
    for (int fn = 0; fn < NF; ++fn)
      #pragma unroll
      for (int j = 0; j < 4; ++j) {
        const int r = mt * BM + wrow * WTM + fm * 16 + lg * 4 + j;
        const int c = wcol * WTN + fn * 16 + l16;
        atomicAdd(&C[(size_t)r * ldc + c], scale * acc[fm][fn][j]);
      }
}

__global__ void conv_w_kernel(const float* __restrict__ W1, const float* __restrict__ W2,
                              unsigned short* __restrict__ W1b, unsigned short* __restrict__ W2b) {
  const int i = blockIdx.x * 256 + threadIdx.x;
  if (i < D_IN * D_HID)  W1b[i] = f2bf(W1[i]);
  if (i < D_HID * D_OUT) W2b[i] = f2bf(W2[i]);
}

// Bext[rows[r], :] = bf16(relu(G[r,:] + bias))   (Bext pre-zeroed)
__global__ void ep_scatter_kernel(const float* __restrict__ G, const float* __restrict__ bias,
                                  const int* __restrict__ rows, unsigned short* __restrict__ Bext,
                                  int ncol, int total4) {
  const int idx = blockIdx.x * 256 + threadIdx.x;
  if (idx >= total4) return;
  const int npc = ncol >> 2;
  const int r  = idx / npc;
  const int c0 = (idx - r * npc) * 4;
  f32x4 g = *(const f32x4*)&G[(size_t)idx * 4];
  const int rg = rows[r];
  ushort4v o;
  #pragma unroll
  for (int j = 0; j < 4; ++j) {
    float v = g[j] + bias[c0 + j];
    v = v > 0.f ? v : 0.f;
    o[j] = f2bf(v);
  }
  *(ushort4v*)&Bext[(size_t)rg * ncol + c0] = o;
}

__global__ void ep_relu_kernel(const float* __restrict__ G, float* __restrict__ R, int total4) {
  const int idx = blockIdx.x * 256 + threadIdx.x;
  if (idx >= total4) return;
  f32x4 g = *(const f32x4*)&G[(size_t)idx * 4];
  #pragma unroll
  for (int j = 0; j < 4; ++j) g[j] = g[j] > 0.f ? g[j] : 0.f;
  *(f32x4*)&R[(size_t)idx * 4] = g;
}

extern "C" void kernel_launch(void* const* d_in, const int* in_sizes, int n_in,
                              void* d_out, int out_size, void* d_ws, size_t ws_size,
                              hipStream_t stream) {
  const float* X     = (const float*)d_in[0];
  const float* A_hat = (const float*)d_in[1];
  const float* W1    = (const float*)d_in[2];
  const float* b1    = (const float*)d_in[3];
  const float* W2    = (const float*)d_in[4];
  const float* b2    = (const float*)d_in[5];
  const int*   l0    = (const int*)d_in[6];
  const int*   l1    = (const int*)d_in[7];
  float* out = (float*)d_out;

  if (ws_size < (size_t)(24u << 20)) return;
  char* ws = (char*)d_ws;
  unsigned short* W1b  = (unsigned short*)(ws);                              // 256 KB
  unsigned short* W2b  = (unsigned short*)(ws + (256 << 10));                // 32 KB
  unsigned short* Hext = (unsigned short*)(ws + (512 << 10));                // 8 MB  [N x D_HID]
  unsigned short* Pext = (unsigned short*)(ws + (512 << 10) + (8  << 20));   // 2 MB  [N x D_OUT]
  float* G1 = (float*)(ws + (512 << 10) + (10 << 20));                       // 4 MB  [S x D_HID]
  float* G2 = (float*)(ws + (512 << 10) + (14 << 20));                       // 4 MB  [S x D_HID]
  float* R1 = (float*)(ws + (512 << 10) + (18 << 20));                       // 4 MB  [S x D_HID]
  float* G3 = (float*)(ws + (512 << 10) + (22 << 20));                       // 1 MB  [S x D_OUT]

  // zero atomic targets + scatter targets (ws/out are poisoned, atomics accumulate)
  hipMemsetAsync(G1,   0, (size_t)S_SAMP * D_HID * 4, stream);
  hipMemsetAsync(G2,   0, (size_t)S_SAMP * D_HID * 4, stream);
  hipMemsetAsync(G3,   0, (size_t)S_SAMP * D_OUT * 4, stream);
  hipMemsetAsync(Hext, 0, (size_t)N_NODES * D_HID * 2, stream);
  hipMemsetAsync(Pext, 0, (size_t)N_NODES * D_OUT * 2, stream);
  hipMemsetAsync(out,  0, (size_t)N_NODES * D_OUT * 4, stream);

  conv_w_kernel<<<512, 256, 0, stream>>>(W1, W2, W1b, W2b);

  // L0: G1 = X[l0] @ W1
  gemm_bf16_atomic<64, 256, 64><<<(S_SAMP / 64) * 4, 256, 0, stream>>>(
      X, D_IN, l0, W1b, D_HID, G1, D_HID, S_SAMP, D_IN, 4, 1.0f);
  // Hext[l0[j]] = bf16(relu(G1[j] + b1))
  ep_scatter_kernel<<<(S_SAMP * D_HID / 4 + 255) / 256, 256, 0, stream>>>(
      G1, b1, l0, Hext, D_HID, S_SAMP * D_HID / 4);

  // L0 agg: G2 = 4 * A_hat[l1, :] @ Hext
  gemm_bf16_atomic<64, 256, 64><<<(S_SAMP / 64) * 8, 256, 0, stream>>>(
      A_hat, N_NODES, l1, Hext, D_HID, G2, D_HID, S_SAMP, N_NODES, 8, 4.0f);
  // R1 = relu(G2)  (inter-layer relu; only sampled_l1 rows matter)
  ep_relu_kernel<<<(S_SAMP * D_HID / 4 + 255) / 256, 256, 0, stream>>>(
      G2, R1, S_SAMP * D_HID / 4);

  // L1: G3 = R1 @ W2
  gemm_bf16_atomic<64, 64, 64><<<(S_SAMP / 64) * 4, 256, 0, stream>>>(
      R1, D_HID, nullptr, W2b, D_OUT, G3, D_OUT, S_SAMP, D_HID, 4, 1.0f);
  // Pext[l1[j]] = bf16(relu(G3[j] + b2))
  ep_scatter_kernel<<<(S_SAMP * D_OUT / 4 + 255) / 256, 256, 0, stream>>>(
      G3, b2, l1, Pext, D_OUT, S_SAMP * D_OUT / 4);

  // L1 agg: out = 4 * A_hat @ Pext
  gemm_bf16_atomic<64, 64, 64><<<(N_NODES / 64) * 8, 256, 0, stream>>>(
      A_hat, N_NODES, nullptr, Pext, D_OUT, out, D_OUT, N_NODES, N_NODES, 8, 4.0f);
}

// Round 2
// 370.261 us; speedup vs baseline: 1.3960x; 1.3960x over previous
//
#include <hip/hip_runtime.h>
#include <hip/hip_bf16.h>
#include <stdint.h>

typedef __attribute__((ext_vector_type(8))) short short8;
typedef __attribute__((ext_vector_type(4))) float f32x4;

#define N_NODES 16384
#define D_IN    512
#define D_HID   256
#define D_OUT   64
#define S_SAMP  4096

__device__ __forceinline__ unsigned short f2bf(float f) {
  __hip_bfloat16 h = __float2bfloat16(f);
  union { __hip_bfloat16 h; unsigned short u; } cv; cv.h = h; return cv.u;
}

// C += scale * bf16(optional-relu(A_f32[gathered rows])) @ Bt^T
// A: [M][lda] f32 (row gather via arow). Bt: [BN][K] bf16 row-major (N==BN).
// C: [M][ldc] f32, pre-zeroed, atomic accumulate. Grid = (M/BM) * kChunks.
template<int BM, int BN, int BK, bool RELU_A>
__global__ __launch_bounds__(256)
void gemm_tn(const float* __restrict__ A, int lda,
             const int* __restrict__ arow,
             const unsigned short* __restrict__ Bt, int ldb,
             float* __restrict__ C, int ldc,
             int K, int kChunks, float scale)
{
  static_assert(BM == 64 && BK == 64 && (BN == 64 || BN == 256), "tile");
  const int mt  = blockIdx.x / kChunks;
  const int kc  = blockIdx.x % kChunks;
  const int kLen = K / kChunks;
  const int k0   = kc * kLen;
  const int tid  = threadIdx.x;
  const int lane = tid & 63;
  const int wid  = tid >> 6;
  const int l16  = lane & 15;
  const int lg   = lane >> 4;

  __shared__ unsigned short As[BM * BK];   // row m, 16B chunk stored at pos g: holds chunk g^(m&7)
  __shared__ unsigned short Bs[BN * BK];   // row n, same XOR-swizzle (achieved via source pre-swizzle)

  constexpr int WN  = (BN == 256) ? 4 : 2;
  constexpr int WM  = 4 / WN;
  constexpr int WTM = BM / WM;
  constexpr int WTN = BN / WN;
  constexpr int MF  = WTM / 16;
  constexpr int NF  = WTN / 16;
  const int wrow = wid / WN;
  const int wcol = wid % WN;

  f32x4 acc[MF][NF] = {};

  // ---- A staging mapping: 256 threads x 16 f32 = 64x64 tile ----
  const int am   = tid >> 2;
  const int aseg = tid & 3;
  const int arowIdx = mt * BM + am;
  const size_t rowg = arow ? (size_t)arow[arowIdx] : (size_t)arowIdx;
  const float* aBase = A + rowg * (size_t)lda + k0 + aseg * 16;

  // ---- B staging: global_load_lds, linear LDS dest + pre-swizzled source ----
  // slab = 8 rows x 128B = 1KB = one wave-issue (64 lanes x 16B).
  // lane l -> row_in_slab = l>>3, chunkpos = l&7; source chunk = (l&7) ^ (row&7),
  // and (row&7) == (l>>3) since slabs are 8-row aligned.
  constexpr int SLABS = BN / 8;
  constexpr int SLABW = SLABS / 4;
  const int brow = lane >> 3;
  const int bcol = 8 * ((lane & 7) ^ brow);
  const unsigned short* bSrcLane = Bt + (size_t)brow * ldb + k0 + bcol;

  for (int ks = 0; ks < kLen; ks += BK) {
    __syncthreads();   // previous compute done; safe to overwrite As/Bs
    // ---- issue B loads (async, no VGPR round-trip) ----
    #pragma unroll
    for (int i = 0; i < SLABW; ++i) {
      const int s = wid * SLABW + i;
      __builtin_amdgcn_global_load_lds(
          (const __attribute__((address_space(1))) uint32_t*)(bSrcLane + (size_t)s * 8 * ldb + ks),
          (__attribute__((address_space(3))) uint32_t*)(&Bs[s * 512]),
          16, 0, 0);
    }
    // ---- stage A: f32 -> bf16 (v_cvt_pk path), swizzled 16B chunks ----
    {
      const float* ap = aBase + ks;
      f32x4 v0 = *(const f32x4*)(ap + 0);
      f32x4 v1 = *(const f32x4*)(ap + 4);
      f32x4 v2 = *(const f32x4*)(ap + 8);
      f32x4 v3 = *(const f32x4*)(ap + 12);
      if (RELU_A) {
        #pragma unroll
        for (int j = 0; j < 4; ++j) {
          v0[j] = fmaxf(v0[j], 0.f); v1[j] = fmaxf(v1[j], 0.f);
          v2[j] = fmaxf(v2[j], 0.f); v3[j] = fmaxf(v3[j], 0.f);
        }
      }
      short8 s0, s1;
      s0[0]=f2bf(v0[0]); s0[1]=f2bf(v0[1]); s0[2]=f2bf(v0[2]); s0[3]=f2bf(v0[3]);
      s0[4]=f2bf(v1[0]); s0[5]=f2bf(v1[1]); s0[6]=f2bf(v1[2]); s0[7]=f2bf(v1[3]);
      s1[0]=f2bf(v2[0]); s1[1]=f2bf(v2[1]); s1[2]=f2bf(v2[2]); s1[3]=f2bf(v2[3]);
      s1[4]=f2bf(v3[0]); s1[5]=f2bf(v3[1]); s1[6]=f2bf(v3[2]); s1[7]=f2bf(v3[3]);
      const int g0 = (aseg * 2)     ^ (am & 7);
      const int g1 = (aseg * 2 + 1) ^ (am & 7);
      *(short8*)&As[am * BK + g0 * 8] = s0;
      *(short8*)&As[am * BK + g1 * 8] = s1;
    }
    __syncthreads();   // drains lgkmcnt (ds_write) AND vmcnt (global_load_lds)
    // ---- compute ----
    #pragma unroll
    for (int kk = 0; kk < BK / 32; ++kk) {
      const int gk = kk * 4 + lg;
      short8 af[MF], bfr[NF];
      #pragma unroll
      for (int fm = 0; fm < MF; ++fm) {
        const int m = wrow * WTM + fm * 16 + l16;
        af[fm] = *(const short8*)&As[m * BK + ((gk ^ (m & 7)) * 8)];
      }
      #pragma unroll
      for (int fn = 0; fn < NF; ++fn) {
        const int n = wcol * WTN + fn * 16 + l16;
        bfr[fn] = *(const short8*)&Bs[n * BK + ((gk ^ (n & 7)) * 8)];
      }
      #pragma unroll
      for (int fm = 0; fm < MF; ++fm)
        #pragma unroll
        for (int fn = 0; fn < NF; ++fn)
          acc[fm][fn] = __builtin_amdgcn_mfma_f32_16x16x32_bf16(
              af[fm], bfr[fn], acc[fm][fn], 0, 0, 0);
    }
  }
  // ---- epilogue: scaled f32 atomic add ----
  #pragma unroll
  for (int fm = 0; fm < MF; ++fm)
    #pragma unroll
    for (int fn = 0; fn < NF; ++fn)
      #pragma unroll
      for (int j = 0; j < 4; ++j) {
        const int r = mt * BM + wrow * WTM + fm * 16 + lg * 4 + j;
        const int c = wcol * WTN + fn * 16 + l16;
        atomicAdd(&C[(size_t)r * ldc + c], scale * acc[fm][fn][j]);
      }
}

// transpose-convert weights: W1t[j][i] = bf16(W1[i][j]), W2t likewise
__global__ void conv_w_t(const float* __restrict__ W1, const float* __restrict__ W2,
                         unsigned short* __restrict__ W1t, unsigned short* __restrict__ W2t) {
  const int idx = blockIdx.x * 256 + threadIdx.x;
  if (idx < D_IN * D_HID) {
    const int j = idx / D_IN, i = idx % D_IN;        // write coalesced along i
    W1t[idx] = f2bf(W1[(size_t)i * D_HID + j]);
  }
  if (idx < D_HID * D_OUT) {
    const int j = idx / D_HID, i = idx % D_HID;
    W2t[idx] = f2bf(W2[(size_t)i * D_OUT + j]);
  }
}

// BextT[c][rows[r]] = bf16(relu(G[r][c] + bias[c]))   (BextT pre-zeroed, [ncol][N_NODES])
__global__ void ep_scatter_t(const float* __restrict__ G, const float* __restrict__ bias,
                             const int* __restrict__ rows, unsigned short* __restrict__ BextT,
                             int ncol, int total) {
  const int idx = blockIdx.x * 256 + threadIdx.x;
  if (idx >= total) return;
  const int c = idx / S_SAMP;        // c uniform per wave -> bias broadcast
  const int r = idx & (S_SAMP - 1);  // consecutive lanes -> same 32KB dest row
  float v = G[(size_t)r * ncol + c] + bias[c];
  v = v > 0.f ? v : 0.f;
  BextT[(size_t)c * N_NODES + rows[r]] = f2bf(v);
}

extern "C" void kernel_launch(void* const* d_in, const int* in_sizes, int n_in,
                              void* d_out, int out_size, void* d_ws, size_t ws_size,
                              hipStream_t stream) {
  const float* X     = (const float*)d_in[0];
  const float* A_hat = (const float*)d_in[1];
  const float* W1    = (const float*)d_in[2];
  const float* b1    = (const float*)d_in[3];
  const float* W2    = (const float*)d_in[4];
  const float* b2    = (const float*)d_in[5];
  const int*   l0    = (const int*)d_in[6];
  const int*   l1    = (const int*)d_in[7];
  float* out = (float*)d_out;

  if (ws_size < (size_t)(20u << 20)) return;
  char* ws = (char*)d_ws;
  // zeroed region: [HextT 8M][PextT 2M][G1 4M][G2 4M][G3 1M] = 19 MB contiguous
  unsigned short* HextT = (unsigned short*)(ws);                      // [256][16384]
  unsigned short* PextT = (unsigned short*)(ws + (8  << 20));         // [64][16384]
  float* G1 = (float*)(ws + (10 << 20));                              // [S][256]
  float* G2 = (float*)(ws + (14 << 20));                              // [S][256]
  float* G3 = (float*)(ws + (18 << 20));                              // [S][64]
  unsigned short* W1t = (unsigned short*)(ws + (19 << 20));           // [256][512]
  unsigned short* W2t = (unsigned short*)(ws + (19 << 20) + (256 << 10)); // [64][256]

  hipMemsetAsync(ws,  0, (size_t)(19u << 20), stream);
  hipMemsetAsync(out, 0, (size_t)N_NODES * D_OUT * 4, stream);

  conv_w_t<<<512, 256, 0, stream>>>(W1, W2, W1t, W2t);

  // L0 feature: G1 = X[l0] @ W1          M=4096 K=512 N=256
  gemm_tn<64, 256, 64, false><<<(S_SAMP / 64) * 4, 256, 0, stream>>>(
      X, D_IN, l0, W1t, D_IN, G1, D_HID, D_IN, 4, 1.0f);
  // HextT[:, l0[j]] = bf16(relu(G1[j] + b1))
  ep_scatter_t<<<(S_SAMP * D_HID + 255) / 256, 256, 0, stream>>>(
      G1, b1, l0, HextT, D_HID, S_SAMP * D_HID);

  // L0 agg: G2 = 4 * A_hat[l1, :] @ Hext  M=4096 K=16384 N=256
  gemm_tn<64, 256, 64, false><<<(S_SAMP / 64) * 8, 256, 0, stream>>>(
      A_hat, N_NODES, l1, HextT, N_NODES, G2, D_HID, N_NODES, 8, 4.0f);

  // L1 feature: G3 = relu(G2) @ W2        M=4096 K=256 N=64  (relu fused into A-path)
  gemm_tn<64, 64, 64, true><<<(S_SAMP / 64) * 4, 256, 0, stream>>>(
      G2, D_HID, nullptr, W2t, D_HID, G3, D_OUT, D_HID, 4, 1.0f);
  // PextT[:, l1[j]] = bf16(relu(G3[j] + b2))
  ep_scatter_t<<<(S_SAMP * D_OUT + 255) / 256, 256, 0, stream>>>(
      G3, b2, l1, PextT, D_OUT, S_SAMP * D_OUT);

  // L1 agg: out = 4 * A_hat @ Pext        M=16384 K=16384 N=64
  gemm_tn<64, 64, 64, false><<<(N_NODES / 64) * 8, 256, 0, stream>>>(
      A_hat, N_NODES, nullptr, PextT, N_NODES, out, D_OUT, N_NODES, 8, 4.0f);
}